// Round 11
// baseline (128.892 us; speedup 1.0000x reference)
//
#include <hip/hip_runtime.h>
#include <stdint.h>

// ReconstructionDecoder, factorized, THREE kernels.
// r5: no device-scope spin barriers. r6/r7: big fusion spills/starves.
// r9: streamed W1 gather = no change. r10: inline-A gemm regressed +14us.
// r11 theory: every slow A/B-fragment build used
//   union{unsigned short u[8]; short8 v;} with loop-indexed writes -> the
//   compiler demotes it to scratch (rule #20), turning ~10 VALU ops into a
//   latency-serialized local-mem round trip per fragment (r0's fast prep
//   used direct u16 stores -> 4us; every union-based build was 45-60us).
//   Fix: build fragments as ext_vector element writes with constant
//   indices (register-guaranteed). Bytes bitwise identical to r10.
//
// Identity: h = xt[bnt] + f[fi] (broadcast sum), W1g = g*W1:
//   LN(h)@W1 + b1 = rs*( (xt@W1g)[e] + (f@W1g)[e] - mu*G[e] ) + K[e]
//   G[e] = sum_k g_k W1[k,e], K[e] = b1[e] + sum_k b_k W1[k,e],
//   mu = (Sxt+Sf)/256, var = (Sxt2 + 2*(xt.f) + Sf2)/256 - mu^2.
// 3-term bf16 split GEMM (stacked K=768): A=[hi|lo|hi], B=[W1hi|W1hi|W1lo].

#define D_ 256
#define E_ 512

typedef __attribute__((ext_vector_type(8))) short short8;
typedef __attribute__((ext_vector_type(4))) float f32x4;
typedef __attribute__((ext_vector_type(2))) float f32x2;

// ---- module-scope scratch (rewritten fully every launch; d_ws untouched) ----
__device__ alignas(16) unsigned short g_Bbuf[768 * 640];   // 0.98 MB
__device__ alignas(16) float g_U[2048 * 512];              // 4 MB
__device__ alignas(16) float g_C[2048 * 128];              // 1 MB
__device__ alignas(16) float g_Vt[512 * 128];              // 256 KB
__device__ alignas(16) float g_GKW[512 * 4];
__device__ alignas(16) float g_sxt[2048];
__device__ alignas(16) float g_sqxt[2048];
__device__ alignas(16) float g_sf[128];
__device__ alignas(16) float g_sqf[128];

__device__ inline unsigned short f2bf(float f) {
  unsigned int u = __float_as_uint(f);
  u += 0x7fffu + ((u >> 16) & 1u);
  return (unsigned short)(u >> 16);
}
__device__ inline float bf2f(unsigned short h) {
  return __uint_as_float(((unsigned int)h) << 16);
}
// hi or lo bf16 of v, selected by compile-time-ish flag (registers only)
__device__ inline short bfsel(float v, bool lo) {
  const unsigned short h = f2bf(v);
  return (short)(lo ? f2bf(v - bf2f(h)) : h);
}

// Build one A-fragment (8 consecutive k's), 3-term hi/lo selection.
// term 0: hi, term 1: lo, term 2: hi  (matches B = [W1hi | W1hi | W1lo]).
// Pure ext_vector element writes with literal indices -> registers.
__device__ inline short8 mk_frag(float4 a0, float4 a1, int term) {
  const bool lo = (term == 1);
  short8 r;
  r[0] = bfsel(a0.x, lo);
  r[1] = bfsel(a0.y, lo);
  r[2] = bfsel(a0.z, lo);
  r[3] = bfsel(a0.w, lo);
  r[4] = bfsel(a1.x, lo);
  r[5] = bfsel(a1.y, lo);
  r[6] = bfsel(a1.z, lo);
  r[7] = bfsel(a1.w, lo);
  return r;
}

// ---------------------------------------------------------------------------
// prep2 block roles (grid 88):
//   [0,48):  Bbuf fragments via LDS-staged coalesced W1/f_emb slabs
//   [48,56): GKW[e] = {G, K, W2[e][0], W2[e][1]}, k-split 4 waves
//   [56,88): stats: 4 waves/block x 17 rows/wave -> sxt/sqxt/sf/sqf
// ---------------------------------------------------------------------------
__global__ __launch_bounds__(256) void prep2(
    const float* __restrict__ x, const float* __restrict__ t_emb,
    const float* __restrict__ f_emb, const float* __restrict__ ln_g,
    const float* __restrict__ ln_b, const float* __restrict__ W1,
    const float* __restrict__ b1, const float* __restrict__ W2) {
  __shared__ float sW[32][264];  // 33.8 KB; 1056B rows, 16B-aligned slots
  __shared__ float sF[128][36];  // 18.0 KB; 144B rows, 16B-aligned slots
  __shared__ float sg[32];
  __shared__ float red[4][64][2];

  const int blk = blockIdx.x;
  const int tid = threadIdx.x;
  const int wv = tid >> 6;
  const int l = tid & 63;

  if (blk < 48) {
    // ---- Bbuf via LDS-staged coalesced slabs ----
    const int b = blk;               // 0..47
    const int kt = b >> 1, h = b & 1;
    const bool lo = (kt >> 3) == 2;  // term 2 -> lo bytes
    const int k0 = (kt & 7) * 32;
    {
      const float4* w4 = (const float4*)(W1 + (size_t)k0 * E_ + h * 256);
      for (int i = tid; i < 2048; i += 256) {
        const int kk2 = i >> 6, c4 = i & 63;
        *(float4*)&sW[kk2][c4 * 4] = w4[kk2 * (E_ / 4) + c4];
      }
      if (tid < 32) sg[tid] = ln_g[k0 + tid];
      if (h == 0) {
        const float4* f4 = (const float4*)(f_emb + k0);
        for (int i = tid; i < 1024; i += 256) {
          const int fr = i >> 3, c4 = i & 7;
          *(float4*)&sF[fr][c4 * 4] = f4[fr * (D_ / 4) + c4];
        }
      }
    }
    __syncthreads();
    // W1-derived fragments: ct = 4h..4h+3, 1024 frags (4/thread)
    for (int fi = tid; fi < 1024; fi += 256) {
      const int ct = 4 * h + (fi >> 8);
      const int rem = fi & 255;
      const int jtl = rem >> 6, ln = rem & 63;
      const int colw = (ct - 4 * h) * 64 + jtl * 16 + (ln & 15);
      const int kb = ((ln >> 4) & 3) * 8;
      short8 fr8;
      fr8[0] = bfsel(sg[kb + 0] * sW[kb + 0][colw], lo);
      fr8[1] = bfsel(sg[kb + 1] * sW[kb + 1][colw], lo);
      fr8[2] = bfsel(sg[kb + 2] * sW[kb + 2][colw], lo);
      fr8[3] = bfsel(sg[kb + 3] * sW[kb + 3][colw], lo);
      fr8[4] = bfsel(sg[kb + 4] * sW[kb + 4][colw], lo);
      fr8[5] = bfsel(sg[kb + 5] * sW[kb + 5][colw], lo);
      fr8[6] = bfsel(sg[kb + 6] * sW[kb + 6][colw], lo);
      fr8[7] = bfsel(sg[kb + 7] * sW[kb + 7][colw], lo);
      const int gidx = ((kt * 10 + ct) * 4 + jtl) * 64 + ln;
      *(short8*)(g_Bbuf + gidx * 8) = fr8;
    }
    if (h == 0) {
      // f_emb-derived fragments: ct 8,9, 512 frags (2/thread)
      for (int fi = tid; fi < 512; fi += 256) {
        const int ct = 8 + (fi >> 8);
        const int rem = fi & 255;
        const int jtl = rem >> 6, ln = rem & 63;
        const int f = (ct - 8) * 64 + jtl * 16 + (ln & 15);
        const int kb = ((ln >> 4) & 3) * 8;
        short8 fr8;
        fr8[0] = bfsel(sF[f][kb + 0], lo);
        fr8[1] = bfsel(sF[f][kb + 1], lo);
        fr8[2] = bfsel(sF[f][kb + 2], lo);
        fr8[3] = bfsel(sF[f][kb + 3], lo);
        fr8[4] = bfsel(sF[f][kb + 4], lo);
        fr8[5] = bfsel(sF[f][kb + 5], lo);
        fr8[6] = bfsel(sF[f][kb + 6], lo);
        fr8[7] = bfsel(sF[f][kb + 7], lo);
        const int gidx = ((kt * 10 + ct) * 4 + jtl) * 64 + ln;
        *(short8*)(g_Bbuf + gidx * 8) = fr8;
      }
    }
  } else if (blk < 56) {
    // ---- GKW: block owns 64 e's; wave w owns k-range [64w,64w+64) ----
    const int e = (blk - 48) * 64 + l;
    const int k0 = wv * 64;
    float G = 0.f, K = 0.f;
#pragma unroll 8
    for (int i = 0; i < 64; ++i) {
      const float wval = W1[(k0 + i) * E_ + e];
      G = fmaf(ln_g[k0 + i], wval, G);
      K = fmaf(ln_b[k0 + i], wval, K);
    }
    red[wv][l][0] = G;
    red[wv][l][1] = K;
    __syncthreads();
    if (wv == 0) {
      G = (red[0][l][0] + red[1][l][0]) + (red[2][l][0] + red[3][l][0]);
      K = (red[0][l][1] + red[1][l][1]) + (red[2][l][1] + red[3][l][1]);
      float4 o;
      o.x = G; o.y = K + b1[e];
      o.z = W2[2 * e]; o.w = W2[2 * e + 1];
      *(float4*)(g_GKW + 4 * e) = o;
    }
  } else {
    // ---- stats: wave handles 17 rows; lane owns elements 4l..4l+3 ----
    const int w0 = ((blk - 56) * 4 + wv) * 17;  // 0,17,...,2159
    for (int i = 0; i < 17; ++i) {
      const int r = w0 + i;  // < 2176
      float v0, v1, v2, v3;
      if (r < 2048) {
        const int bn = r >> 7, t = r & 127;
        const float4 xv = *(const float4*)(x + bn * D_ + 4 * l);
        const float4 tv = *(const float4*)(t_emb + t * D_ + 4 * l);
        v0 = xv.x + tv.x; v1 = xv.y + tv.y;
        v2 = xv.z + tv.z; v3 = xv.w + tv.w;
      } else {
        const float4 fv = *(const float4*)(f_emb + (r - 2048) * D_ + 4 * l);
        v0 = fv.x; v1 = fv.y; v2 = fv.z; v3 = fv.w;
      }
      float s = (v0 + v1) + (v2 + v3);
      float q = fmaf(v0, v0, fmaf(v1, v1, fmaf(v2, v2, v3 * v3)));
#pragma unroll
      for (int d = 1; d < 64; d <<= 1) {
        s += __shfl_xor(s, d);
        q += __shfl_xor(q, d);
      }
      if (l == 0) {
        if (r < 2048) { g_sxt[r] = s; g_sqxt[r] = q; }
        else          { g_sf[r - 2048] = s; g_sqf[r - 2048] = q; }
      }
    }
  }
}

// ---------------------------------------------------------------------------
// gemm3c: [2176 x 768] @ [768 x 640], 128x64 tiles, grid 17x10 = 170.
// A-fragments built INLINE (registers only) from x/t_emb (rt<16) or f_emb
// (rt==16). B fragments MFMA-ordered in g_Bbuf, straight global->VGPR.
// No LDS, no barriers. Output: rt<16,ct<8 -> U; ct>=8 -> C; rt==16 -> Vt.
// ---------------------------------------------------------------------------
__global__ __launch_bounds__(256) void gemm3c(const float* __restrict__ x,
                                              const float* __restrict__ t_emb,
                                              const float* __restrict__ f_emb) {
  const int tid = threadIdx.x;
  const int wave = tid >> 6, lane = tid & 63;
  const int quad = (lane >> 4) & 3, n16 = lane & 15;
  const int rt = blockIdx.x / 10, ct = blockIdx.x % 10;
  const int rowb = rt * 128 + wave * 32;

  const float* base0;  // row rowb+n16
  const float* base1;  // row rowb+16+n16
  const float* xrow;   // block-uniform additive part (rt<16 only)
  if (rt < 16) {
    base0 = t_emb + (size_t)(wave * 32 + n16) * D_;
    base1 = base0 + 16 * D_;
    xrow = x + (size_t)rt * D_;
  } else {
    base0 = f_emb + (size_t)(wave * 32 + n16) * D_;
    base1 = base0 + 16 * D_;
    xrow = nullptr;
  }

  f32x4 acc[2][4];
#pragma unroll
  for (int j = 0; j < 4; ++j) {
    acc[0][j] = (f32x4){0.f, 0.f, 0.f, 0.f};
    acc[1][j] = (f32x4){0.f, 0.f, 0.f, 0.f};
  }

#pragma unroll 4
  for (int kt = 0; kt < 24; ++kt) {
    const int term = kt >> 3;                  // 0:hi 1:lo 2:hi (A-side)
    const int kb = (kt & 7) * 32 + quad * 8;   // 8 consecutive k's
    float4 t0a = *(const float4*)(base0 + kb);
    float4 t0b = *(const float4*)(base0 + kb + 4);
    float4 t1a = *(const float4*)(base1 + kb);
    float4 t1b = *(const float4*)(base1 + kb + 4);
    if (rt < 16) {  // block-uniform branch
      const float4 xa = *(const float4*)(xrow + kb);
      const float4 xb = *(const float4*)(xrow + kb + 4);
      t0a.x += xa.x; t0a.y += xa.y; t0a.z += xa.z; t0a.w += xa.w;
      t0b.x += xb.x; t0b.y += xb.y; t0b.z += xb.z; t0b.w += xb.w;
      t1a.x += xa.x; t1a.y += xa.y; t1a.z += xa.z; t1a.w += xa.w;
      t1b.x += xb.x; t1b.y += xb.y; t1b.z += xb.z; t1b.w += xb.w;
    }
    const short8 av0 = mk_frag(t0a, t0b, term);
    const short8 av1 = mk_frag(t1a, t1b, term);
    const short8* bp = (const short8*)g_Bbuf + ((kt * 10 + ct) * 4) * 64 + lane;
#pragma unroll
    for (int jtl = 0; jtl < 4; ++jtl) {
      const short8 bf = bp[jtl * 64];
      acc[0][jtl] =
          __builtin_amdgcn_mfma_f32_16x16x32_bf16(av0, bf, acc[0][jtl], 0, 0, 0);
      acc[1][jtl] =
          __builtin_amdgcn_mfma_f32_16x16x32_bf16(av1, bf, acc[1][jtl], 0, 0, 0);
    }
  }

#pragma unroll
  for (int g = 0; g < 2; ++g)
#pragma unroll
    for (int jtl = 0; jtl < 4; ++jtl)
#pragma unroll
      for (int r = 0; r < 4; ++r) {
        const float val = acc[g][jtl][r];
        const int grow = rowb + g * 16 + quad * 4 + r;  // C/D: row=quad*4+reg
        const int col = ct * 64 + jtl * 16 + n16;        //      col=lane&15
        if (rt < 16) {
          if (ct < 8) g_U[grow * 512 + col] = val;
          else        g_C[grow * 128 + (col - 512)] = val;
        } else if (ct < 8) {
          g_Vt[col * 128 + (grow - 2048)] = val;  // transposed store (tiny)
        }
      }
}

// ---------------------------------------------------------------------------
// decode2 (proven): packed-f32 VALU pass. Block = 4 rows, 8 waves.
// Wave w owns e-slice [64w,64w+64); lane owns f-pair {2l,2l+1} as f32x2.
// pre = Ar*(U+V) + (Br*G + K) via v_pk_fma_f32; relu; fold W2; LDS reduce.
// ---------------------------------------------------------------------------
__global__ __launch_bounds__(512) void decode2(const float* __restrict__ b2,
                                               float* __restrict__ out) {
  __shared__ float part[8][64][17];  // 34.8KB partials
  const int tid = threadIdx.x;
  const int w = tid >> 6, lane = tid & 63;
  const int bnt0 = blockIdx.x * 4;

  const f32x2 sf2 = *(const f32x2*)(g_sf + 2 * lane);
  const f32x2 sqf2 = *(const f32x2*)(g_sqf + 2 * lane);
  f32x2 Ar[4], Br[4];
#pragma unroll
  for (int ti = 0; ti < 4; ++ti) {
    const float sx = g_sxt[bnt0 + ti];
    const float sqx = g_sqxt[bnt0 + ti];
    const f32x2 c2 = *(const f32x2*)(g_C + (bnt0 + ti) * 128 + 2 * lane);
    const f32x2 mu = (sf2 + sx) * (1.0f / 256.0f);
    const f32x2 var = (sqf2 + 2.0f * c2 + sqx) * (1.0f / 256.0f) - mu * mu;
    f32x2 rs;
    rs.x = rsqrtf(var.x + 1e-5f);
    rs.y = rsqrtf(var.y + 1e-5f);
    Ar[ti] = rs;
    Br[ti] = -rs * mu;
  }

  f32x2 o0[4] = {(f32x2){0.f, 0.f}, (f32x2){0.f, 0.f},
                 (f32x2){0.f, 0.f}, (f32x2){0.f, 0.f}};
  f32x2 o1[4] = {(f32x2){0.f, 0.f}, (f32x2){0.f, 0.f},
                 (f32x2){0.f, 0.f}, (f32x2){0.f, 0.f}};
  const int ebase = __builtin_amdgcn_readfirstlane(w * 64);
#pragma unroll 8
  for (int ei = 0; ei < 64; ++ei) {
    const int e = ebase + ei;
    const float4 gkw = *(const float4*)(g_GKW + 4 * e);           // s_load
    const f32x2 v2 = *(const f32x2*)(g_Vt + e * 128 + 2 * lane);  // coalesced
#pragma unroll
    for (int ti = 0; ti < 4; ++ti) {
      const float u = g_U[(bnt0 + ti) * 512 + e];  // wave-uniform s_load
      const f32x2 s = v2 + u;                                   // pk_add
      const f32x2 pre = Ar[ti] * s + (Br[ti] * gkw.x + gkw.y);  // pk_fma x2
      f32x2 y;
      y.x = fmaxf(pre.x, 0.f);
      y.y = fmaxf(pre.y, 0.f);
      o0[ti] += y * gkw.z;  // pk_fma
      o1[ti] += y * gkw.w;  // pk_fma
    }
  }

#pragma unroll
  for (int ti = 0; ti < 4; ++ti) {
    part[w][lane][ti * 4 + 0] = o0[ti].x;  // f even, ch0
    part[w][lane][ti * 4 + 1] = o1[ti].x;  // f even, ch1
    part[w][lane][ti * 4 + 2] = o0[ti].y;  // f odd,  ch0
    part[w][lane][ti * 4 + 3] = o1[ti].y;  // f odd,  ch1
  }
  __syncthreads();

  const int t = tid >> 7, f = tid & 127;
  const int m = f >> 1, ff = f & 1;
  float r0 = b2[0], r1 = b2[1];
#pragma unroll
  for (int w2 = 0; w2 < 8; ++w2) {
    r0 += part[w2][m][t * 4 + ff * 2 + 0];
    r1 += part[w2][m][t * 4 + ff * 2 + 1];
  }
  float2 res;
  res.x = r0;
  res.y = r1;
  *(float2*)(out + ((bnt0 + t) * 128 + f) * 2) = res;
}

// ---------------------------------------------------------------------------
extern "C" void kernel_launch(void* const* d_in, const int* in_sizes, int n_in,
                              void* d_out, int out_size, void* d_ws,
                              size_t ws_size, hipStream_t stream) {
  const float* x = (const float*)d_in[0];
  const float* t_emb = (const float*)d_in[1];
  const float* f_emb = (const float*)d_in[2];
  const float* ln_g = (const float*)d_in[3];
  const float* ln_b = (const float*)d_in[4];
  const float* W1 = (const float*)d_in[5];
  const float* b1 = (const float*)d_in[6];
  const float* W2 = (const float*)d_in[7];
  const float* b2 = (const float*)d_in[8];
  (void)d_ws; (void)ws_size;

  prep2<<<88, 256, 0, stream>>>(x, t_emb, f_emb, ln_g, ln_b, W1, b1, W2);
  gemm3c<<<170, 256, 0, stream>>>(x, t_emb, f_emb);
  decode2<<<512, 512, 0, stream>>>(b2, (float*)d_out);
}

// Round 12
// 113.590 us; speedup vs baseline: 1.1347x; 1.1347x over previous
//
#include <hip/hip_runtime.h>
#include <stdint.h>

// ReconstructionDecoder, factorized, THREE kernels (r9 structure = best).
// r5: no device-scope spin barriers. r6/r7: fusion spills (r7 FETCH=6.6GB!).
// r9: Bbuf scatter vs streamed = no change. r10/r11: inline-A gemm slow.
// r12 theory: decode2's inner loop issues 5 wave-uniform SCALAR loads per
//   e-iter (4 U rows + GKW) against MALL-resident cross-XCD data (~600-800
//   cyc); 320 s_loads/wave on the critical path = the hidden ~35-45us.
//   Fix (only change vs r9): stage the block's 4 U-rows (8KB, contiguous)
//   + GKW (8KB) into LDS in the prologue; hot loop reads LDS broadcasts.
//
// Identity: h = xt[bnt] + f[fi] (broadcast sum), W1g = g*W1:
//   LN(h)@W1 + b1 = rs*( (xt@W1g)[e] + (f@W1g)[e] - mu*G[e] ) + K[e]
//   G[e] = sum_k g_k W1[k,e], K[e] = b1[e] + sum_k b_k W1[k,e],
//   mu = (Sxt+Sf)/256, var = (Sxt2 + 2*(xt.f) + Sf2)/256 - mu^2.
// 3-term bf16 split GEMM (stacked K=768): A=[hi|lo|hi], B=[W1hi|W1hi|W1lo].

#define D_ 256
#define E_ 512

typedef __attribute__((ext_vector_type(8))) short short8;
typedef __attribute__((ext_vector_type(4))) short short4v;
typedef __attribute__((ext_vector_type(4))) float f32x4;
typedef __attribute__((ext_vector_type(2))) float f32x2;

// ---- module-scope scratch (rewritten fully every launch; d_ws untouched) ----
__device__ alignas(16) unsigned short g_Abuf[2176 * 768];  // 3.34 MB
__device__ alignas(16) unsigned short g_Bbuf[768 * 640];   // 0.98 MB
__device__ alignas(16) float g_U[2048 * 512];              // 4 MB
__device__ alignas(16) float g_C[2048 * 128];              // 1 MB
__device__ alignas(16) float g_Vt[512 * 128];              // 256 KB
__device__ alignas(16) float g_GKW[512 * 4];
__device__ alignas(16) float g_sxt[2048];
__device__ alignas(16) float g_sqxt[2048];
__device__ alignas(16) float g_sf[128];
__device__ alignas(16) float g_sqf[128];

__device__ inline unsigned short f2bf(float f) {
  unsigned int u = __float_as_uint(f);
  u += 0x7fffu + ((u >> 16) & 1u);
  return (unsigned short)(u >> 16);
}
__device__ inline float bf2f(unsigned short h) {
  return __uint_as_float(((unsigned int)h) << 16);
}

// ---------------------------------------------------------------------------
// prep (grid 600) — r9-proven:
//   [0,512):   xt rows -> Abuf rows 0..2047 as [hi|lo|hi] + Sxt/Sxt2
//   [512,544): f rows  -> Abuf rows 2048..2175 as [hi|lo|hi] + Sf/Sf2
//   [544,552): GKW[e] = {G, K, W2[e][0], W2[e][1]}, k-split 4 waves
//   [552,600): Bbuf fragments via LDS-staged coalesced W1/f_emb slabs
// ---------------------------------------------------------------------------
__global__ __launch_bounds__(256) void prep(
    const float* __restrict__ x, const float* __restrict__ t_emb,
    const float* __restrict__ f_emb, const float* __restrict__ ln_g,
    const float* __restrict__ ln_b, const float* __restrict__ W1,
    const float* __restrict__ b1, const float* __restrict__ W2) {
  __shared__ float sW[32][264];  // 33.8 KB; 1056B rows, 16B-aligned slots
  __shared__ float sF[128][36];  // 18.0 KB; 144B rows, 16B-aligned slots
  __shared__ float sg[32];
  __shared__ float red[4][64][2];

  const int blk = blockIdx.x;
  const int tid = threadIdx.x;
  const int wv = tid >> 6;
  const int l = tid & 63;

  if (blk < 544) {
    // ---- rows: 4 rows/block, 1 row/wave ----
    int arow;
    float v0, v1, v2, v3;
    if (blk < 512) {
      const int r = blk * 4 + wv;  // 0..2047
      const int bn = r >> 7, t = r & 127;
      const float4 xv = *(const float4*)(x + bn * D_ + 4 * l);
      const float4 tv = *(const float4*)(t_emb + t * D_ + 4 * l);
      v0 = xv.x + tv.x; v1 = xv.y + tv.y;
      v2 = xv.z + tv.z; v3 = xv.w + tv.w;
      arow = r;
    } else {
      const int fi = (blk - 512) * 4 + wv;  // 0..127
      const float4 fv = *(const float4*)(f_emb + fi * D_ + 4 * l);
      v0 = fv.x; v1 = fv.y; v2 = fv.z; v3 = fv.w;
      arow = 2048 + fi;
    }
    union { unsigned short u[4]; short4v v; } hi, lo;
    hi.u[0] = f2bf(v0); hi.u[1] = f2bf(v1);
    hi.u[2] = f2bf(v2); hi.u[3] = f2bf(v3);
    lo.u[0] = f2bf(v0 - bf2f(hi.u[0]));
    lo.u[1] = f2bf(v1 - bf2f(hi.u[1]));
    lo.u[2] = f2bf(v2 - bf2f(hi.u[2]));
    lo.u[3] = f2bf(v3 - bf2f(hi.u[3]));
    unsigned short* ab = g_Abuf + arow * 768 + 4 * l;
    *(short4v*)(ab) = hi.v;        // cols [0,256):   hi
    *(short4v*)(ab + 256) = lo.v;  // cols [256,512): lo
    *(short4v*)(ab + 512) = hi.v;  // cols [512,768): hi
    float s = (v0 + v1) + (v2 + v3);
    float q = fmaf(v0, v0, fmaf(v1, v1, fmaf(v2, v2, v3 * v3)));
#pragma unroll
    for (int d = 1; d < 64; d <<= 1) {
      s += __shfl_xor(s, d);
      q += __shfl_xor(q, d);
    }
    if (l == 0) {
      if (arow < 2048) { g_sxt[arow] = s; g_sqxt[arow] = q; }
      else             { g_sf[arow - 2048] = s; g_sqf[arow - 2048] = q; }
    }
  } else if (blk < 552) {
    // ---- GKW: block owns 64 e's; wave w owns k-range [64w,64w+64) ----
    const int e = (blk - 544) * 64 + l;
    const int k0 = wv * 64;
    float G = 0.f, K = 0.f;
#pragma unroll 8
    for (int i = 0; i < 64; ++i) {
      const float wval = W1[(k0 + i) * E_ + e];
      G = fmaf(ln_g[k0 + i], wval, G);
      K = fmaf(ln_b[k0 + i], wval, K);
    }
    red[wv][l][0] = G;
    red[wv][l][1] = K;
    __syncthreads();
    if (wv == 0) {
      G = (red[0][l][0] + red[1][l][0]) + (red[2][l][0] + red[3][l][0]);
      K = (red[0][l][1] + red[1][l][1]) + (red[2][l][1] + red[3][l][1]);
      float4 o;
      o.x = G; o.y = K + b1[e];
      o.z = W2[2 * e]; o.w = W2[2 * e + 1];
      *(float4*)(g_GKW + 4 * e) = o;
    }
  } else {
    // ---- Bbuf via LDS-staged coalesced slabs ----
    const int b = blk - 552;         // 0..47
    const int kt = b >> 1, h = b & 1;
    const int term = kt >> 3;        // 0,1: hi; 2: lo
    const int k0 = (kt & 7) * 32;
    {
      const float4* w4 = (const float4*)(W1 + (size_t)k0 * E_ + h * 256);
      for (int i = tid; i < 2048; i += 256) {
        const int kk2 = i >> 6, c4 = i & 63;
        *(float4*)&sW[kk2][c4 * 4] = w4[kk2 * (E_ / 4) + c4];
      }
      if (tid < 32) sg[tid] = ln_g[k0 + tid];
      if (h == 0) {
        const float4* f4 = (const float4*)(f_emb + k0);
        for (int i = tid; i < 1024; i += 256) {
          const int fr = i >> 3, c4 = i & 7;
          *(float4*)&sF[fr][c4 * 4] = f4[fr * (D_ / 4) + c4];
        }
      }
    }
    __syncthreads();
    for (int fi = tid; fi < 1024; fi += 256) {
      const int ct = 4 * h + (fi >> 8);
      const int rem = fi & 255;
      const int jtl = rem >> 6, ln = rem & 63;
      const int colw = (ct - 4 * h) * 64 + jtl * 16 + (ln & 15);
      const int kb = ((ln >> 4) & 3) * 8;
      union { unsigned short u[8]; short8 v; } fr8;
#pragma unroll
      for (int j = 0; j < 8; ++j) {
        const float v = sg[kb + j] * sW[kb + j][colw];
        const unsigned short hv = f2bf(v);
        fr8.u[j] = (term == 2) ? f2bf(v - bf2f(hv)) : hv;
      }
      const int gidx = ((kt * 10 + ct) * 4 + jtl) * 64 + ln;
      *(short8*)(g_Bbuf + gidx * 8) = fr8.v;
    }
    if (h == 0) {
      for (int fi = tid; fi < 512; fi += 256) {
        const int ct = 8 + (fi >> 8);
        const int rem = fi & 255;
        const int jtl = rem >> 6, ln = rem & 63;
        const int f = (ct - 8) * 64 + jtl * 16 + (ln & 15);
        const int kb = ((ln >> 4) & 3) * 8;
        union { unsigned short u[8]; short8 v; } fr8;
#pragma unroll
        for (int j = 0; j < 8; ++j) {
          const float v = sF[f][kb + j];
          const unsigned short hv = f2bf(v);
          fr8.u[j] = (term == 2) ? f2bf(v - bf2f(hv)) : hv;
        }
        const int gidx = ((kt * 10 + ct) * 4 + jtl) * 64 + ln;
        *(short8*)(g_Bbuf + gidx * 8) = fr8.v;
      }
    }
  }
}

// ---------------------------------------------------------------------------
// gemm3 (r3/r9-proven): [2176 x 768] @ [768 x 640], 128x64 tiles, grid 17x10.
// B fragments MFMA-ordered, straight global->VGPR, no LDS, no barriers.
// Output: rt<16,ct<8 -> U; rt<16,ct>=8 -> C; rt==16,ct<8 -> Vt.
// ---------------------------------------------------------------------------
__global__ __launch_bounds__(256) void gemm3() {
  const int tid = threadIdx.x;
  const int wave = tid >> 6, lane = tid & 63;
  const int quad = (lane >> 4) & 3, n16 = lane & 15;
  const int rt = blockIdx.x / 10, ct = blockIdx.x % 10;
  const int rowb = rt * 128 + wave * 32;

  const unsigned short* a0 = g_Abuf + (size_t)(rowb + n16) * 768 + quad * 8;
  const unsigned short* a1 = a0 + 16 * 768;

  f32x4 acc[2][4];
#pragma unroll
  for (int j = 0; j < 4; ++j) {
    acc[0][j] = (f32x4){0.f, 0.f, 0.f, 0.f};
    acc[1][j] = (f32x4){0.f, 0.f, 0.f, 0.f};
  }

#pragma unroll 4
  for (int kt = 0; kt < 24; ++kt) {
    const short8 av0 = *(const short8*)(a0 + kt * 32);
    const short8 av1 = *(const short8*)(a1 + kt * 32);
    const short8* bp = (const short8*)g_Bbuf + ((kt * 10 + ct) * 4) * 64 + lane;
#pragma unroll
    for (int jtl = 0; jtl < 4; ++jtl) {
      const short8 bf = bp[jtl * 64];
      acc[0][jtl] =
          __builtin_amdgcn_mfma_f32_16x16x32_bf16(av0, bf, acc[0][jtl], 0, 0, 0);
      acc[1][jtl] =
          __builtin_amdgcn_mfma_f32_16x16x32_bf16(av1, bf, acc[1][jtl], 0, 0, 0);
    }
  }

#pragma unroll
  for (int g = 0; g < 2; ++g)
#pragma unroll
    for (int jtl = 0; jtl < 4; ++jtl)
#pragma unroll
      for (int r = 0; r < 4; ++r) {
        const float val = acc[g][jtl][r];
        const int grow = rowb + g * 16 + quad * 4 + r;  // C/D: row=quad*4+reg
        const int col = ct * 64 + jtl * 16 + n16;        //      col=lane&15
        if (rt < 16) {
          if (ct < 8) g_U[grow * 512 + col] = val;
          else        g_C[grow * 128 + (col - 512)] = val;
        } else if (ct < 8) {
          g_Vt[col * 128 + (grow - 2048)] = val;  // transposed store (tiny)
        }
      }
}

// ---------------------------------------------------------------------------
// decode2 (r12 change): packed-f32 VALU pass with LDS-staged U and GKW.
// Block = 4 rows, 8 waves. Prologue: stage the block's 4 U-rows (8KB,
// contiguous in g_U -> coalesced float4) + full GKW table (8KB) into LDS.
// Hot loop: u/gkw from LDS broadcast (no SMEM latency chain); only the
// coalesced per-lane Vt vector load stays global.
// ---------------------------------------------------------------------------
__global__ __launch_bounds__(512) void decode2(const float* __restrict__ b2,
                                               float* __restrict__ out) {
  __shared__ alignas(16) float sU[4][512];     // 8 KB
  __shared__ alignas(16) float sGKW[512 * 4];  // 8 KB
  __shared__ float part[8][64][17];            // 34.8 KB (total 50.8 KB)
  const int tid = threadIdx.x;
  const int w = tid >> 6, lane = tid & 63;
  const int bnt0 = blockIdx.x * 4;

  // stage: rows bnt0..bnt0+3 of U are contiguous 2048 floats = 512 float4
  ((float4*)sU)[tid] = ((const float4*)(g_U + (size_t)bnt0 * 512))[tid];
  ((float4*)sGKW)[tid] = ((const float4*)g_GKW)[tid];

  const f32x2 sf2 = *(const f32x2*)(g_sf + 2 * lane);
  const f32x2 sqf2 = *(const f32x2*)(g_sqf + 2 * lane);
  f32x2 Ar[4], Br[4];
#pragma unroll
  for (int ti = 0; ti < 4; ++ti) {
    const float sx = g_sxt[bnt0 + ti];
    const float sqx = g_sqxt[bnt0 + ti];
    const f32x2 c2 = *(const f32x2*)(g_C + (bnt0 + ti) * 128 + 2 * lane);
    const f32x2 mu = (sf2 + sx) * (1.0f / 256.0f);
    const f32x2 var = (sqf2 + 2.0f * c2 + sqx) * (1.0f / 256.0f) - mu * mu;
    f32x2 rs;
    rs.x = rsqrtf(var.x + 1e-5f);
    rs.y = rsqrtf(var.y + 1e-5f);
    Ar[ti] = rs;
    Br[ti] = -rs * mu;
  }
  __syncthreads();  // sU/sGKW staged

  f32x2 o0[4] = {(f32x2){0.f, 0.f}, (f32x2){0.f, 0.f},
                 (f32x2){0.f, 0.f}, (f32x2){0.f, 0.f}};
  f32x2 o1[4] = {(f32x2){0.f, 0.f}, (f32x2){0.f, 0.f},
                 (f32x2){0.f, 0.f}, (f32x2){0.f, 0.f}};
  const int ebase = __builtin_amdgcn_readfirstlane(w * 64);
#pragma unroll 8
  for (int ei = 0; ei < 64; ++ei) {
    const int e = ebase + ei;
    const float4 gkw = *(const float4*)(sGKW + 4 * e);            // LDS bcast
    const f32x2 v2 = *(const f32x2*)(g_Vt + e * 128 + 2 * lane);  // coalesced
#pragma unroll
    for (int ti = 0; ti < 4; ++ti) {
      const float u = sU[ti][e];  // LDS broadcast (wave-uniform addr)
      const f32x2 s = v2 + u;                                   // pk_add
      const f32x2 pre = Ar[ti] * s + (Br[ti] * gkw.x + gkw.y);  // pk_fma x2
      f32x2 y;
      y.x = fmaxf(pre.x, 0.f);
      y.y = fmaxf(pre.y, 0.f);
      o0[ti] += y * gkw.z;  // pk_fma
      o1[ti] += y * gkw.w;  // pk_fma
    }
  }

#pragma unroll
  for (int ti = 0; ti < 4; ++ti) {
    part[w][lane][ti * 4 + 0] = o0[ti].x;  // f even, ch0
    part[w][lane][ti * 4 + 1] = o1[ti].x;  // f even, ch1
    part[w][lane][ti * 4 + 2] = o0[ti].y;  // f odd,  ch0
    part[w][lane][ti * 4 + 3] = o1[ti].y;  // f odd,  ch1
  }
  __syncthreads();

  const int t = tid >> 7, f = tid & 127;
  const int m = f >> 1, ff = f & 1;
  float r0 = b2[0], r1 = b2[1];
#pragma unroll
  for (int w2 = 0; w2 < 8; ++w2) {
    r0 += part[w2][m][t * 4 + ff * 2 + 0];
    r1 += part[w2][m][t * 4 + ff * 2 + 1];
  }
  float2 res;
  res.x = r0;
  res.y = r1;
  *(float2*)(out + ((bnt0 + t) * 128 + f) * 2) = res;
}

// ---------------------------------------------------------------------------
extern "C" void kernel_launch(void* const* d_in, const int* in_sizes, int n_in,
                              void* d_out, int out_size, void* d_ws,
                              size_t ws_size, hipStream_t stream) {
  const float* x = (const float*)d_in[0];
  const float* t_emb = (const float*)d_in[1];
  const float* f_emb = (const float*)d_in[2];
  const float* ln_g = (const float*)d_in[3];
  const float* ln_b = (const float*)d_in[4];
  const float* W1 = (const float*)d_in[5];
  const float* b1 = (const float*)d_in[6];
  const float* W2 = (const float*)d_in[7];
  const float* b2 = (const float*)d_in[8];
  (void)d_ws; (void)ws_size;

  prep<<<600, 256, 0, stream>>>(x, t_emb, f_emb, ln_g, ln_b, W1, b1, W2);
  gemm3<<<170, 256, 0, stream>>>();
  decode2<<<512, 512, 0, stream>>>(b2, (float*)d_out);
}